// Round 16
// baseline (3161.810 us; speedup 1.0000x reference)
//
#include <hip/hip_runtime.h>
#include <math.h>

// Problem constants
#define Bsz 32
#define Tt  512
#define Isz 256
#define Hsz 512
#define G3  1536
#define Osz 128

// Fused 3-role pipeline: 192 blocks x 512 threads (all co-resident).
//  role 0 (blocks   0..63): L0  rec  (Whh0)        -> y0 ring  pbuf0[8]
//  role 1 (blocks  64..127): L1x proj (Wih1+bih1)  -> xq ring  xqbuf[8]
//  role 2 (blocks 128..191): L1h rec  (Whh1)       -> h1 dbuf  pbuf1[2], hall
// Block (bg,p): batches 4bg..4bg+3, h-cols [64p,64p+64).
// Thread (jl=tid>>3, kc=tid&7): col j=64p+jl, k in [64kc,+64) -> 192 wfloats.
// Gen scheme: state at time t carries gen t+1. y0[t]=h0(t+1): gen t+2 in
// pbuf0 slot (t+1)&7. xq[t]: gen t+2 in xqbuf slot (t+1)&7 (3 gates adjacent
// per (b,col)). h1(t): gen t+1 in pbuf1 slot t&1.
// Back-pressure (round-8 proven pattern: check BEFORE publish, gated by sync):
//  L0 step t needs min(prog0[bg][*]) >= t-7 ; L1x step t needs prog1[bg][p] >= t-7.
#define TPB  512
#define NFUSED 192
#define POLL_GUARD (1 << 22)
#define BH  (Bsz * Hsz)      // 16384 pairs per pbuf slot
#define XQP (Bsz * G3)       // 49152 pairs per xq slot

typedef float f4 __attribute__((ext_vector_type(4)));
typedef float f32x4 __attribute__((ext_vector_type(4)));
typedef _Float16 half8_t __attribute__((ext_vector_type(8)));
typedef _Float16 half4_t __attribute__((ext_vector_type(4)));
typedef unsigned int u32;
typedef u32 u32x2 __attribute__((ext_vector_type(2)));
typedef u32 u32x4 __attribute__((ext_vector_type(4)));

__device__ __forceinline__ float sigf(float x) { return 1.0f / (1.0f + expf(-x)); }

// ---------------- f32 -> f16 (weights for the xp MFMA GEMM) ----------------
__global__ void f32_to_f16(const float* __restrict__ in, _Float16* __restrict__ out, int n4) {
    int i = threadIdx.x + blockIdx.x * blockDim.x;
    int stride = blockDim.x * gridDim.x;
    for (int k = i; k < n4; k += stride) {
        float4 v = reinterpret_cast<const float4*>(in)[k];
        half4_t o;
        o[0] = (_Float16)v.x; o[1] = (_Float16)v.y;
        o[2] = (_Float16)v.z; o[3] = (_Float16)v.w;
        reinterpret_cast<half4_t*>(out)[k] = o;
    }
}

// ---------------- init all exchange buffers ----------------
__global__ void init_bufs(u32x2* pbuf0, u32x2* pbuf1, u32x2* xqbuf,
                          int* prog0, int* prog1) {
    int i = threadIdx.x + blockIdx.x * blockDim.x;
    int stride = blockDim.x * gridDim.x;
    for (int k = i; k < 8 * BH; k += stride)
        pbuf0[k] = (k < BH) ? (u32x2){0u, 1u} : (u32x2){0u, 0u};
    for (int k = i; k < 2 * BH; k += stride)
        pbuf1[k] = (k < BH) ? (u32x2){0u, 1u} : (u32x2){0u, 0u};
    for (int k = i; k < 8 * XQP; k += stride)
        xqbuf[k] = (u32x2){0u, 0u};
    for (int k = i; k < 1024; k += stride) { prog0[k] = 0; prog1[k] = 0; }
}

// ---------------- fused 3-role persistent pipeline ----------------
__global__ void __launch_bounds__(TPB, 1) gru_fused(
    const float* __restrict__ xp,     // [B*T,3H] layer-0 input proj (incl bih0)
    const float* __restrict__ Whh0, const float* __restrict__ bhh0,
    const float* __restrict__ Wih1, const float* __restrict__ bih1,
    const float* __restrict__ Whh1, const float* __restrict__ bhh1,
    float* __restrict__ hall,         // [B*T,H] layer-1 outputs
    u32x2* __restrict__ pbuf0,        // [8][BH]
    u32x2* __restrict__ pbuf1,        // [2][BH]
    u32x2* __restrict__ xqbuf,        // [8][XQP] idx ((b*512+col)*3+g)
    int* __restrict__ prog0,          // [64*16]
    int* __restrict__ prog1,          // [64*16]
    float* __restrict__ hid)          // [2*B*H]
{
    const int tid  = threadIdx.x;
    const int rid  = blockIdx.x;
    const int role = rid >> 6;
    const int loc  = rid & 63;
    const int bg   = loc >> 3;           // batch group (4 batches)
    const int p    = loc & 7;            // col group (64 cols)
    const int jl   = tid >> 3;           // 0..63
    const int kc   = tid & 7;            // 0..7
    const int j    = p * 64 + jl;
    const int li   = (tid >> 6) * 68 + (tid & 63);
    const int lo   = (j >> 6) * 68 + (j & 63);

    __shared__ float hs[4 * 544];        // 4 batches x 512 (68-padded chunks)

    if (role == 0) {
        // ================= L0: layer-0 recurrence =================
        f4 w[3][16];
        #pragma unroll
        for (int g = 0; g < 3; ++g) {
            const float* wp = Whh0 + (size_t)(g * Hsz + j) * Hsz + kc * 64;
            #pragma unroll
            for (int q = 0; q < 16; ++q) w[g][q] = *reinterpret_cast<const f4*>(wp + q * 4);
        }
        #pragma unroll
        for (int g = 0; g < 3; ++g)
            #pragma unroll
            for (int q = 0; q < 16; ++q) asm volatile("" : "+v"(w[g][q]));
        const float b0 = bhh0[j], b1 = bhh0[Hsz + j], b2 = bhh0[2 * Hsz + j];
        int bpk = 0;

        for (int t = 0; t < Tt; ++t) {
            const u32 rg = (u32)(t + 1), wgen = rg + 1u;
            const u32x2* src = pbuf0 + (size_t)(t & 7) * BH + bg * 4 * Hsz;
            u32x2*       dst = pbuf0 + (size_t)((t + 1) & 7) * BH + bg * 4 * Hsz;

            float xr[4], xz[4], xn[4];
            if (kc == 0) {
                #pragma unroll
                for (int bi = 0; bi < 4; ++bi) {
                    const float* pp = xp + (size_t)((bg * 4 + bi) * Tt + t) * G3;
                    xr[bi] = pp[j]; xz[bi] = pp[Hsz + j]; xn[bi] = pp[2 * Hsz + j];
                }
            }

            // poll h0(t): 4 pairs (one per batch)
            {
                const u32x2* a0 = src + 0 * Hsz + tid;
                const u32x2* a1 = src + 1 * Hsz + tid;
                const u32x2* a2 = src + 2 * Hsz + tid;
                const u32x2* a3 = src + 3 * Hsz + tid;
                u32x2 r0, r1, r2, r3;
                int guard = 0;
                for (;;) {
                    asm volatile(
                        "global_load_dwordx2 %0, %4, off sc0 sc1\n\t"
                        "global_load_dwordx2 %1, %5, off sc0 sc1\n\t"
                        "global_load_dwordx2 %2, %6, off sc0 sc1\n\t"
                        "global_load_dwordx2 %3, %7, off sc0 sc1\n\t"
                        "s_waitcnt vmcnt(0)"
                        : "=&v"(r0), "=&v"(r1), "=&v"(r2), "=&v"(r3)
                        : "v"(a0), "v"(a1), "v"(a2), "v"(a3) : "memory");
                    bool ok = (r0[1] == rg) && (r1[1] == rg) && (r2[1] == rg) && (r3[1] == rg);
                    if (__all(ok) || ++guard > POLL_GUARD) break;
                    __builtin_amdgcn_s_sleep(1);
                }
                hs[0 * 544 + li] = __uint_as_float(r0[0]);
                hs[1 * 544 + li] = __uint_as_float(r1[0]);
                hs[2 * 544 + li] = __uint_as_float(r2[0]);
                hs[3 * 544 + li] = __uint_as_float(r3[0]);
            }
            __syncthreads();

            // back-pressure BEFORE publish: need min(prog0[bg][*]) >= t-7
            {
                const int thr = t - 7;
                if (tid < 64 && thr > bpk) {
                    const int* pp = prog0 + ((bg << 3) + (tid & 7)) * 16;
                    int guard = 0;
                    for (;;) {
                        int v;
                        asm volatile("global_load_dword %0, %1, off sc0 sc1\n\t"
                                     "s_waitcnt vmcnt(0)" : "=&v"(v) : "v"(pp) : "memory");
                        int mv = (tid < 8) ? v : 0x7fffffff;
                        #pragma unroll
                        for (int off = 1; off < 8; off <<= 1) {
                            int o = __shfl_xor(mv, off, 64);
                            mv = (o < mv) ? o : mv;
                        }
                        mv = __shfl(mv, 0, 64);
                        if (mv >= thr || ++guard > POLL_GUARD) { bpk = mv; break; }
                        __builtin_amdgcn_s_sleep(2);
                    }
                }
            }
            __syncthreads();   // gate ALL publishes on back-pressure

            #pragma unroll
            for (int bi = 0; bi < 4; ++bi) {
                float a0 = 0.f, a1 = 0.f, a2 = 0.f;
                const f4* hp = reinterpret_cast<const f4*>(hs + bi * 544) + kc * 17;
                #pragma unroll
                for (int q = 0; q < 16; ++q) {
                    f4 hv4 = hp[q];
                    a0 = fmaf(w[0][q][0], hv4[0], a0); a0 = fmaf(w[0][q][1], hv4[1], a0);
                    a0 = fmaf(w[0][q][2], hv4[2], a0); a0 = fmaf(w[0][q][3], hv4[3], a0);
                    a1 = fmaf(w[1][q][0], hv4[0], a1); a1 = fmaf(w[1][q][1], hv4[1], a1);
                    a1 = fmaf(w[1][q][2], hv4[2], a1); a1 = fmaf(w[1][q][3], hv4[3], a1);
                    a2 = fmaf(w[2][q][0], hv4[0], a2); a2 = fmaf(w[2][q][1], hv4[1], a2);
                    a2 = fmaf(w[2][q][2], hv4[2], a2); a2 = fmaf(w[2][q][3], hv4[3], a2);
                }
                #pragma unroll
                for (int off = 1; off < 8; off <<= 1) {
                    a0 += __shfl_xor(a0, off, 64);
                    a1 += __shfl_xor(a1, off, 64);
                    a2 += __shfl_xor(a2, off, 64);
                }
                if (kc == 0) {
                    float rr = sigf(xr[bi] + a0 + b0);
                    float zz = sigf(xz[bi] + a1 + b1);
                    float nn = tanhf(xn[bi] + rr * (a2 + b2));
                    float ho = hs[bi * 544 + lo];
                    float hv = (1.0f - zz) * nn + zz * ho;
                    u32x2 pk = (u32x2){__float_as_uint(hv), wgen};
                    asm volatile("global_store_dwordx2 %0, %1, off sc0 sc1"
                                 :: "v"(dst + bi * Hsz + j), "v"(pk) : "memory");
                    if (t == Tt - 1) hid[(bg * 4 + bi) * Hsz + j] = hv;
                }
            }
            __syncthreads();
        }
    } else if (role == 1) {
        // ================= L1x: xq[t] = Wih1 . y0[t] + bih1 =================
        f4 w[3][16];
        #pragma unroll
        for (int g = 0; g < 3; ++g) {
            const float* wp = Wih1 + (size_t)(g * Hsz + j) * Hsz + kc * 64;
            #pragma unroll
            for (int q = 0; q < 16; ++q) w[g][q] = *reinterpret_cast<const f4*>(wp + q * 4);
        }
        #pragma unroll
        for (int g = 0; g < 3; ++g)
            #pragma unroll
            for (int q = 0; q < 16; ++q) asm volatile("" : "+v"(w[g][q]));
        const float b0 = bih1[j], b1 = bih1[Hsz + j], b2 = bih1[2 * Hsz + j];
        int bpk = 0;

        for (int t = 0; t < Tt; ++t) {
            const u32 rgp = (u32)(t + 2);          // gen of y0[t]; also xq gen
            const u32x2* src = pbuf0 + (size_t)((t + 1) & 7) * BH + bg * 4 * Hsz;
            u32x2* xdst = xqbuf + (size_t)((t + 1) & 7) * XQP;

            // poll y0[t]: 4 pairs
            {
                const u32x2* a0 = src + 0 * Hsz + tid;
                const u32x2* a1 = src + 1 * Hsz + tid;
                const u32x2* a2 = src + 2 * Hsz + tid;
                const u32x2* a3 = src + 3 * Hsz + tid;
                u32x2 r0, r1, r2, r3;
                int guard = 0;
                for (;;) {
                    asm volatile(
                        "global_load_dwordx2 %0, %4, off sc0 sc1\n\t"
                        "global_load_dwordx2 %1, %5, off sc0 sc1\n\t"
                        "global_load_dwordx2 %2, %6, off sc0 sc1\n\t"
                        "global_load_dwordx2 %3, %7, off sc0 sc1\n\t"
                        "s_waitcnt vmcnt(0)"
                        : "=&v"(r0), "=&v"(r1), "=&v"(r2), "=&v"(r3)
                        : "v"(a0), "v"(a1), "v"(a2), "v"(a3) : "memory");
                    bool ok = (r0[1] == rgp) && (r1[1] == rgp) && (r2[1] == rgp) && (r3[1] == rgp);
                    if (__all(ok) || ++guard > POLL_GUARD) break;
                    __builtin_amdgcn_s_sleep(1);
                }
                hs[0 * 544 + li] = __uint_as_float(r0[0]);
                hs[1 * 544 + li] = __uint_as_float(r1[0]);
                hs[2 * 544 + li] = __uint_as_float(r2[0]);
                hs[3 * 544 + li] = __uint_as_float(r3[0]);
            }
            __syncthreads();

            // publish consumption progress + back-pressure for the xq ring
            if (tid == 0) {
                int pv = t + 1;
                asm volatile("global_store_dword %0, %1, off sc0 sc1"
                             :: "v"(prog0 + ((bg << 3) + p) * 16), "v"(pv) : "memory");
                const int thr = t - 7;
                if (thr > bpk) {
                    const int* pp = prog1 + ((bg << 3) + p) * 16;
                    int guard = 0;
                    for (;;) {
                        int v;
                        asm volatile("global_load_dword %0, %1, off sc0 sc1\n\t"
                                     "s_waitcnt vmcnt(0)" : "=&v"(v) : "v"(pp) : "memory");
                        if (v >= thr || ++guard > POLL_GUARD) { bpk = v; break; }
                        __builtin_amdgcn_s_sleep(2);
                    }
                }
            }
            __syncthreads();   // gate publishes

            #pragma unroll
            for (int bi = 0; bi < 4; ++bi) {
                float a0 = 0.f, a1 = 0.f, a2 = 0.f;
                const f4* hp = reinterpret_cast<const f4*>(hs + bi * 544) + kc * 17;
                #pragma unroll
                for (int q = 0; q < 16; ++q) {
                    f4 hv4 = hp[q];
                    a0 = fmaf(w[0][q][0], hv4[0], a0); a0 = fmaf(w[0][q][1], hv4[1], a0);
                    a0 = fmaf(w[0][q][2], hv4[2], a0); a0 = fmaf(w[0][q][3], hv4[3], a0);
                    a1 = fmaf(w[1][q][0], hv4[0], a1); a1 = fmaf(w[1][q][1], hv4[1], a1);
                    a1 = fmaf(w[1][q][2], hv4[2], a1); a1 = fmaf(w[1][q][3], hv4[3], a1);
                    a2 = fmaf(w[2][q][0], hv4[0], a2); a2 = fmaf(w[2][q][1], hv4[1], a2);
                    a2 = fmaf(w[2][q][2], hv4[2], a2); a2 = fmaf(w[2][q][3], hv4[3], a2);
                }
                #pragma unroll
                for (int off = 1; off < 8; off <<= 1) {
                    a0 += __shfl_xor(a0, off, 64);
                    a1 += __shfl_xor(a1, off, 64);
                    a2 += __shfl_xor(a2, off, 64);
                }
                if (kc == 0) {
                    float v0 = a0 + b0, v1 = a1 + b1, v2 = a2 + b2;
                    u32x4 pk0 = (u32x4){__float_as_uint(v0), rgp, __float_as_uint(v1), rgp};
                    u32x2 pk1 = (u32x2){__float_as_uint(v2), rgp};
                    u32x2* xa = xdst + (size_t)((bg * 4 + bi) * Hsz + j) * 3;
                    asm volatile(
                        "global_store_dwordx4 %0, %1, off sc0 sc1\n\t"
                        "global_store_dwordx2 %0, %2, off offset:16 sc0 sc1"
                        :: "v"(xa), "v"(pk0), "v"(pk1) : "memory");
                }
            }
            __syncthreads();
        }
    } else {
        // ================= L1h: layer-1 recurrence =================
        f4 w[3][16];
        #pragma unroll
        for (int g = 0; g < 3; ++g) {
            const float* wp = Whh1 + (size_t)(g * Hsz + j) * Hsz + kc * 64;
            #pragma unroll
            for (int q = 0; q < 16; ++q) w[g][q] = *reinterpret_cast<const f4*>(wp + q * 4);
        }
        #pragma unroll
        for (int g = 0; g < 3; ++g)
            #pragma unroll
            for (int q = 0; q < 16; ++q) asm volatile("" : "+v"(w[g][q]));
        const float b0 = bhh1[j], b1 = bhh1[Hsz + j], b2 = bhh1[2 * Hsz + j];

        for (int t = 0; t < Tt; ++t) {
            const u32 rg = (u32)(t + 1), wgen = rg + 1u, rgx = rg + 1u;
            const u32x2* src = pbuf1 + (size_t)(t & 1) * BH + bg * 4 * Hsz;
            u32x2*       dst = pbuf1 + (size_t)((t + 1) & 1) * BH + bg * 4 * Hsz;
            const u32x2* xsrc = xqbuf + (size_t)((t + 1) & 7) * XQP;

            // early async issue of xq loads (owners): land during the h1 poll
            u32x4 xa_[4]; u32x2 xb_[4];
            const u32x2* xaddr[4];
            #pragma unroll
            for (int bi = 0; bi < 4; ++bi)
                xaddr[bi] = xsrc + (size_t)((bg * 4 + bi) * Hsz + j) * 3;
            if (kc == 0) {
                #pragma unroll
                for (int bi = 0; bi < 4; ++bi)
                    asm volatile(
                        "global_load_dwordx4 %0, %2, off sc0 sc1\n\t"
                        "global_load_dwordx2 %1, %2, off offset:16 sc0 sc1"
                        : "=&v"(xa_[bi]), "=&v"(xb_[bi]) : "v"(xaddr[bi]) : "memory");
            }

            // poll h1(t): 4 pairs
            {
                const u32x2* a0 = src + 0 * Hsz + tid;
                const u32x2* a1 = src + 1 * Hsz + tid;
                const u32x2* a2 = src + 2 * Hsz + tid;
                const u32x2* a3 = src + 3 * Hsz + tid;
                u32x2 r0, r1, r2, r3;
                int guard = 0;
                for (;;) {
                    asm volatile(
                        "global_load_dwordx2 %0, %4, off sc0 sc1\n\t"
                        "global_load_dwordx2 %1, %5, off sc0 sc1\n\t"
                        "global_load_dwordx2 %2, %6, off sc0 sc1\n\t"
                        "global_load_dwordx2 %3, %7, off sc0 sc1\n\t"
                        "s_waitcnt vmcnt(0)"
                        : "=&v"(r0), "=&v"(r1), "=&v"(r2), "=&v"(r3)
                        : "v"(a0), "v"(a1), "v"(a2), "v"(a3) : "memory");
                    bool ok = (r0[1] == rg) && (r1[1] == rg) && (r2[1] == rg) && (r3[1] == rg);
                    if (__all(ok) || ++guard > POLL_GUARD) break;
                    __builtin_amdgcn_s_sleep(1);
                }
                hs[0 * 544 + li] = __uint_as_float(r0[0]);
                hs[1 * 544 + li] = __uint_as_float(r1[0]);
                hs[2 * 544 + li] = __uint_as_float(r2[0]);
                hs[3 * 544 + li] = __uint_as_float(r3[0]);
            }

            // validate xq (usually already arrived); pass-through waitcnt orders checks
            {
                int guard = 0;
                for (;;) {
                    asm volatile("s_waitcnt vmcnt(0)"
                                 : "+v"(xa_[0]), "+v"(xb_[0]), "+v"(xa_[1]), "+v"(xb_[1]),
                                   "+v"(xa_[2]), "+v"(xb_[2]), "+v"(xa_[3]), "+v"(xb_[3])
                                 :: "memory");
                    bool okx = true;
                    if (kc == 0) {
                        #pragma unroll
                        for (int bi = 0; bi < 4; ++bi)
                            okx = okx && (xa_[bi][1] == rgx) && (xa_[bi][3] == rgx)
                                      && (xb_[bi][1] == rgx);
                    }
                    bool c = (kc != 0) || okx;
                    if (__all(c) || ++guard > POLL_GUARD) break;
                    if (kc == 0) {
                        #pragma unroll
                        for (int bi = 0; bi < 4; ++bi)
                            asm volatile(
                                "global_load_dwordx4 %0, %2, off sc0 sc1\n\t"
                                "global_load_dwordx2 %1, %2, off offset:16 sc0 sc1"
                                : "=&v"(xa_[bi]), "=&v"(xb_[bi]) : "v"(xaddr[bi]) : "memory");
                    }
                    __builtin_amdgcn_s_sleep(1);
                }
            }
            __syncthreads();

            // release L1x back-pressure: xq[t] consumed (held in registers)
            if (tid == 0) {
                int pv = t + 1;
                asm volatile("global_store_dword %0, %1, off sc0 sc1"
                             :: "v"(prog1 + ((bg << 3) + p) * 16), "v"(pv) : "memory");
            }

            #pragma unroll
            for (int bi = 0; bi < 4; ++bi) {
                float g0 = 0.f, g1 = 0.f, g2 = 0.f;
                const f4* hp = reinterpret_cast<const f4*>(hs + bi * 544) + kc * 17;
                #pragma unroll
                for (int q = 0; q < 16; ++q) {
                    f4 hv4 = hp[q];
                    g0 = fmaf(w[0][q][0], hv4[0], g0); g0 = fmaf(w[0][q][1], hv4[1], g0);
                    g0 = fmaf(w[0][q][2], hv4[2], g0); g0 = fmaf(w[0][q][3], hv4[3], g0);
                    g1 = fmaf(w[1][q][0], hv4[0], g1); g1 = fmaf(w[1][q][1], hv4[1], g1);
                    g1 = fmaf(w[1][q][2], hv4[2], g1); g1 = fmaf(w[1][q][3], hv4[3], g1);
                    g2 = fmaf(w[2][q][0], hv4[0], g2); g2 = fmaf(w[2][q][1], hv4[1], g2);
                    g2 = fmaf(w[2][q][2], hv4[2], g2); g2 = fmaf(w[2][q][3], hv4[3], g2);
                }
                #pragma unroll
                for (int off = 1; off < 8; off <<= 1) {
                    g0 += __shfl_xor(g0, off, 64);
                    g1 += __shfl_xor(g1, off, 64);
                    g2 += __shfl_xor(g2, off, 64);
                }
                if (kc == 0) {
                    float xr = __uint_as_float(xa_[bi][0]);
                    float xz = __uint_as_float(xa_[bi][2]);
                    float xn = __uint_as_float(xb_[bi][0]);
                    float rr = sigf(xr + g0 + b0);
                    float zz = sigf(xz + g1 + b1);
                    float nn = tanhf(xn + rr * (g2 + b2));
                    float ho = hs[bi * 544 + lo];
                    float hv = (1.0f - zz) * nn + zz * ho;
                    u32x2 pk = (u32x2){__float_as_uint(hv), wgen};
                    asm volatile("global_store_dwordx2 %0, %1, off sc0 sc1"
                                 :: "v"(dst + bi * Hsz + j), "v"(pk) : "memory");
                    hall[(size_t)((bg * 4 + bi) * Tt + t) * Hsz + j] = hv;
                    if (t == Tt - 1) hid[BH + (bg * 4 + bi) * Hsz + j] = hv;
                }
            }
            __syncthreads();
        }
    }
}

// ---------------- f16-MFMA GEMM: C[M,N] = A[M,K]_f32 * Wh[N,K]_f16^T + bias ----
__global__ void __launch_bounds__(256) gemm_nt_mfma(
    const float* __restrict__ A, const _Float16* __restrict__ Wh,
    const float* __restrict__ bias, float* __restrict__ C,
    int M, int N, int K)
{
    const int tid = threadIdx.x;
    const int l   = tid & 63;
    const int w   = tid >> 6;
    const int wm  = w >> 1, wn = w & 1;
    const int m0  = blockIdx.y * 128 + wm * 64;
    const int n0  = blockIdx.x * 128 + wn * 64;
    const int lr  = l & 15;
    const int lk  = (l >> 4) * 8;

    f32x4 acc[4][4];
    #pragma unroll
    for (int mt = 0; mt < 4; ++mt)
        #pragma unroll
        for (int nt = 0; nt < 4; ++nt)
            acc[mt][nt] = (f32x4){0.f, 0.f, 0.f, 0.f};

    for (int ks = 0; ks < K; ks += 32) {
        half8_t af[4], bf[4];
        #pragma unroll
        for (int mt = 0; mt < 4; ++mt) {
            const float* pa = A + (size_t)(m0 + mt * 16 + lr) * K + ks + lk;
            float4 v0 = *reinterpret_cast<const float4*>(pa);
            float4 v1 = *reinterpret_cast<const float4*>(pa + 4);
            half8_t h;
            h[0] = (_Float16)v0.x; h[1] = (_Float16)v0.y;
            h[2] = (_Float16)v0.z; h[3] = (_Float16)v0.w;
            h[4] = (_Float16)v1.x; h[5] = (_Float16)v1.y;
            h[6] = (_Float16)v1.z; h[7] = (_Float16)v1.w;
            af[mt] = h;
        }
        #pragma unroll
        for (int nt = 0; nt < 4; ++nt)
            bf[nt] = *reinterpret_cast<const half8_t*>(Wh + (size_t)(n0 + nt * 16 + lr) * K + ks + lk);
        #pragma unroll
        for (int mt = 0; mt < 4; ++mt)
            #pragma unroll
            for (int nt = 0; nt < 4; ++nt)
                acc[mt][nt] = __builtin_amdgcn_mfma_f32_16x16x32_f16(af[mt], bf[nt], acc[mt][nt], 0, 0, 0);
    }

    #pragma unroll
    for (int nt = 0; nt < 4; ++nt) {
        const int colg = n0 + nt * 16 + lr;
        const float bb = bias[colg];
        #pragma unroll
        for (int mt = 0; mt < 4; ++mt) {
            #pragma unroll
            for (int r = 0; r < 4; ++r) {
                int rowg = m0 + mt * 16 + (l >> 4) * 4 + r;
                C[(size_t)rowg * N + colg] = acc[mt][nt][r] + bb;
            }
        }
    }
}

// ---------------- fp32 GEMM (FC only): C = A * W^T + bias ----------------
#define GM 64
#define GN 64
#define GK 16
__global__ void __launch_bounds__(256) gemm_nt_bias(
    const float* __restrict__ A, const float* __restrict__ W,
    const float* __restrict__ bias, float* __restrict__ C,
    int M, int N, int K)
{
    __shared__ float As[GK][GM];
    __shared__ float Bs[GK][GN];
    const int tid = threadIdx.x;
    const int n0 = blockIdx.x * GN;
    const int m0 = blockIdx.y * GM;
    const int tn = tid & 15;
    const int tm = tid >> 4;
    const int lrow = tid >> 2;
    const int lkq  = tid & 3;

    float acc[4][4];
    #pragma unroll
    for (int i = 0; i < 4; ++i)
        #pragma unroll
        for (int jj = 0; jj < 4; ++jj) acc[i][jj] = 0.0f;

    for (int k0 = 0; k0 < K; k0 += GK) {
        float4 av = *reinterpret_cast<const float4*>(&A[(size_t)(m0 + lrow) * K + k0 + lkq * 4]);
        float4 wv = *reinterpret_cast<const float4*>(&W[(size_t)(n0 + lrow) * K + k0 + lkq * 4]);
        __syncthreads();
        As[lkq * 4 + 0][lrow] = av.x; As[lkq * 4 + 1][lrow] = av.y;
        As[lkq * 4 + 2][lrow] = av.z; As[lkq * 4 + 3][lrow] = av.w;
        Bs[lkq * 4 + 0][lrow] = wv.x; Bs[lkq * 4 + 1][lrow] = wv.y;
        Bs[lkq * 4 + 2][lrow] = wv.z; Bs[lkq * 4 + 3][lrow] = wv.w;
        __syncthreads();
        #pragma unroll
        for (int k = 0; k < GK; ++k) {
            float4 a4 = *reinterpret_cast<const float4*>(&As[k][tm * 4]);
            float4 b4 = *reinterpret_cast<const float4*>(&Bs[k][tn * 4]);
            acc[0][0] = fmaf(a4.x, b4.x, acc[0][0]); acc[0][1] = fmaf(a4.x, b4.y, acc[0][1]);
            acc[0][2] = fmaf(a4.x, b4.z, acc[0][2]); acc[0][3] = fmaf(a4.x, b4.w, acc[0][3]);
            acc[1][0] = fmaf(a4.y, b4.x, acc[1][0]); acc[1][1] = fmaf(a4.y, b4.y, acc[1][1]);
            acc[1][2] = fmaf(a4.y, b4.z, acc[1][2]); acc[1][3] = fmaf(a4.y, b4.w, acc[1][3]);
            acc[2][0] = fmaf(a4.z, b4.x, acc[2][0]); acc[2][1] = fmaf(a4.z, b4.y, acc[2][1]);
            acc[2][2] = fmaf(a4.z, b4.z, acc[2][2]); acc[2][3] = fmaf(a4.z, b4.w, acc[2][3]);
            acc[3][0] = fmaf(a4.w, b4.x, acc[3][0]); acc[3][1] = fmaf(a4.w, b4.y, acc[3][1]);
            acc[3][2] = fmaf(a4.w, b4.z, acc[3][2]); acc[3][3] = fmaf(a4.w, b4.w, acc[3][3]);
        }
    }

    float4 bb = *reinterpret_cast<const float4*>(&bias[n0 + tn * 4]);
    #pragma unroll
    for (int i = 0; i < 4; ++i) {
        int m = m0 + tm * 4 + i;
        float4 o;
        o.x = acc[i][0] + bb.x; o.y = acc[i][1] + bb.y;
        o.z = acc[i][2] + bb.z; o.w = acc[i][3] + bb.w;
        *reinterpret_cast<float4*>(&C[(size_t)m * N + n0 + tn * 4]) = o;
    }
}

// ---------------- host launcher ----------------
extern "C" void kernel_launch(void* const* d_in, const int* in_sizes, int n_in,
                              void* d_out, int out_size, void* d_ws, size_t ws_size,
                              hipStream_t stream) {
    (void)in_sizes; (void)n_in; (void)out_size; (void)ws_size;
    const float* x    = (const float*)d_in[0];
    const float* Wih0 = (const float*)d_in[1];
    const float* Whh0 = (const float*)d_in[2];
    const float* bih0 = (const float*)d_in[3];
    const float* bhh0 = (const float*)d_in[4];
    const float* Wih1 = (const float*)d_in[5];
    const float* Whh1 = (const float*)d_in[6];
    const float* bih1 = (const float*)d_in[7];
    const float* bhh1 = (const float*)d_in[8];
    const float* fcW  = (const float*)d_in[9];
    const float* fcb  = (const float*)d_in[10];

    float* out = (float*)d_out;                       // [B,T,O]
    float* hid = out + (size_t)Bsz * Tt * Osz;        // [L,B,H]

    char* ws = (char*)d_ws;
    const size_t xp_off    = 0;
    const size_t hall_off  = xp_off + (size_t)Bsz * Tt * G3 * 4;       // 100663296
    const size_t pbuf0_off = hall_off + (size_t)Bsz * Tt * Hsz * 4;    // +33554432
    const size_t pbuf1_off = pbuf0_off + (size_t)8 * BH * 8;           // +1048576
    const size_t xq_off    = pbuf1_off + (size_t)2 * BH * 8;           // +262144
    const size_t w0h_off   = xq_off + (size_t)8 * XQP * 8;             // +3145728
    const size_t prog0_off = w0h_off + (size_t)G3 * Isz * 2;           // +786432
    const size_t prog1_off = prog0_off + 4096;
    float*     xp    = (float*)(ws + xp_off);
    float*     hall  = (float*)(ws + hall_off);
    u32x2*     pbuf0 = (u32x2*)(ws + pbuf0_off);
    u32x2*     pbuf1 = (u32x2*)(ws + pbuf1_off);
    u32x2*     xqbuf = (u32x2*)(ws + xq_off);
    _Float16*  W0h   = (_Float16*)(ws + w0h_off);
    int*       prog0 = (int*)(ws + prog0_off);
    int*       prog1 = (int*)(ws + prog1_off);

    // convert Wih0 to f16, then layer-0 input projection (f16 MFMA)
    hipLaunchKernelGGL(f32_to_f16, dim3(128), dim3(256), 0, stream, Wih0, W0h, G3 * Isz / 4);
    hipLaunchKernelGGL(gemm_nt_mfma, dim3(G3 / 128, (Bsz * Tt) / 128), dim3(256), 0, stream,
                       x, W0h, bih0, xp, Bsz * Tt, G3, Isz);

    // init exchange state, then the fused 3-role pipeline
    hipLaunchKernelGGL(init_bufs, dim3(128), dim3(256), 0, stream,
                       pbuf0, pbuf1, xqbuf, prog0, prog1);
    hipLaunchKernelGGL(gru_fused, dim3(NFUSED), dim3(TPB), 0, stream,
                       xp, Whh0, bhh0, Wih1, bih1, Whh1, bhh1,
                       hall, pbuf0, pbuf1, xqbuf, prog0, prog1, hid);

    // FC (fp32): out = hall @ fcW^T + fcb
    hipLaunchKernelGGL(gemm_nt_bias, dim3(Osz / GN, (Bsz * Tt) / GM), dim3(256), 0, stream,
                       hall, fcW, fcb, out, Bsz * Tt, Osz, Hsz);
}

// Round 17
// 1998.853 us; speedup vs baseline: 1.5818x; 1.5818x over previous
//
#include <hip/hip_runtime.h>
#include <math.h>

// Problem constants
#define Bsz 32
#define Tt  512
#define Isz 256
#define Hsz 512
#define G3  1536
#define Osz 128

// Recurrence (round-13 proven): 256 blocks = 32 batches x 8 col-groups;
// 512 threads/block. Device-coherent (sc0 sc1) gen-tagged (val,gen) pairs.
// Round-17 delta: double-buffered LDS h -> ONE __syncthreads per step.
// (Safety: staging step t+2 into buf0 requires passing sync(t+1), which
// requires all threads finished step-t compute reads of buf0.)
#define NBLK 256
#define TPB  512
#define G0_L0 1u
#define G0_L1 4096u
#define POLL_GUARD (1 << 22)

typedef float f4  __attribute__((ext_vector_type(4)));
typedef float f32x4 __attribute__((ext_vector_type(4)));
typedef _Float16 half8_t __attribute__((ext_vector_type(8)));
typedef _Float16 half4_t __attribute__((ext_vector_type(4)));
typedef unsigned int u32;
typedef u32 u32x2 __attribute__((ext_vector_type(2)));

__device__ __forceinline__ float sigf(float x) { return 1.0f / (1.0f + expf(-x)); }

// ---------------- f32 -> f16 conversion (weights, exact RNE casts) ----------------
__global__ void f32_to_f16(const float* __restrict__ in, _Float16* __restrict__ out, int n4) {
    int i = threadIdx.x + blockIdx.x * blockDim.x;
    int stride = blockDim.x * gridDim.x;
    for (int k = i; k < n4; k += stride) {
        float4 v = reinterpret_cast<const float4*>(in)[k];
        half4_t o;
        o[0] = (_Float16)v.x; o[1] = (_Float16)v.y;
        o[2] = (_Float16)v.z; o[3] = (_Float16)v.w;
        reinterpret_cast<half4_t*>(out)[k] = o;
    }
}

// ---------------- init pbuf: slot0 = (h0=0, gen0), slot1 = invalid ----------------
__global__ void init_pbuf(u32x2* pbuf, u32 gen0) {
    int i = threadIdx.x + blockIdx.x * blockDim.x;
    const int n = Bsz * Hsz;
    for (; i < n; i += gridDim.x * blockDim.x) {
        pbuf[i]     = (u32x2){0u, gen0};
        pbuf[n + i] = (u32x2){0u, 0u};
    }
}

// ---------------- persistent GRU recurrence (one layer), batch-split ----------------
// Block (b,p): batch b, h-cols [p*64, p*64+64). Thread (jl=tid>>3, kc=tid&7):
// col j=p*64+jl, k-range [kc*64, +64). 192 weight floats/thread; each thread
// polls exactly one (val,gen) pair per step (simple proven poll).
__global__ void __launch_bounds__(TPB, 2) gru_rec(
    const float* __restrict__ xp,    // [B*T, 3H] (includes b_ih)
    const float* __restrict__ Whh,   // [3H, H]
    const float* __restrict__ bhh,   // [3H]
    float* __restrict__ hall,        // [B*T, H]
    u32x2* __restrict__ pbuf,        // [2][B*H] (val,gen)
    float* __restrict__ hid_out,     // [B*H]
    u32 g0)
{
    const int tid = threadIdx.x;
    const int b   = blockIdx.x & 31;
    const int p   = blockIdx.x >> 5;
    const int jl  = tid >> 3;
    const int kc  = tid & 7;
    const int j   = p * 64 + jl;

    __shared__ float hsh[2][8 * 68];   // double-buffered h (68-padded chunks)

    // ---- load weights: rows {g*H+j}, k in [kc*64, +64)  -> 48 f4 = 192 floats ----
    f4 wreg[3][16];
    #pragma unroll
    for (int g = 0; g < 3; ++g) {
        const float* wp = Whh + (size_t)(g * Hsz + j) * Hsz + kc * 64;
        #pragma unroll
        for (int q = 0; q < 16; ++q)
            wreg[g][q] = *reinterpret_cast<const f4*>(wp + q * 4);
    }
    #pragma unroll
    for (int g = 0; g < 3; ++g)
        #pragma unroll
        for (int q = 0; q < 16; ++q)
            asm volatile("" : "+v"(wreg[g][q]));

    const float bh0 = bhh[0 * Hsz + j];
    const float bh1 = bhh[1 * Hsz + j];
    const float bh2 = bhh[2 * Hsz + j];

    const int li = (tid >> 6) * 68 + (tid & 63);   // staging index
    const int lo = (j >> 6) * 68 + (j & 63);       // own col's h index

    for (int t = 0; t < Tt; ++t) {
        const u32 rg = g0 + (u32)t;
        const u32 wg = rg + 1u;
        const u32x2* src = pbuf + (size_t)(t & 1) * (Bsz * Hsz) + b * Hsz;
        u32x2*       dst = pbuf + (size_t)((t + 1) & 1) * (Bsz * Hsz) + b * Hsz;
        float* hb = &hsh[t & 1][0];

        // xp for owner lanes (plain cached loads; issued before poll)
        float xr = 0.f, xz = 0.f, xn = 0.f;
        if (kc == 0) {
            const float* pp = xp + (size_t)(b * Tt + t) * G3;
            xr = pp[j];
            xz = pp[Hsz + j];
            xn = pp[2 * Hsz + j];
        }

        // ---- poll own pair (1 per thread, per-wave convergence), stage to LDS ----
        {
            const u32x2* sp = src + tid;
            int guard = 0;
            for (;;) {
                u32x2 pr;
                asm volatile("global_load_dwordx2 %0, %1, off sc0 sc1\n\t"
                             "s_waitcnt vmcnt(0)"
                             : "=&v"(pr) : "v"(sp) : "memory");
                if (__all(pr[1] == rg) || ++guard > POLL_GUARD) {
                    hb[li] = __uint_as_float(pr[0]);
                    break;
                }
                __builtin_amdgcn_s_sleep(1);
            }
        }
        __syncthreads();   // the only barrier per step (double-buffer kills the WAR)

        // ---- compute: 3 gate partials over k in [kc*64, +64) ----
        float a0 = 0.f, a1 = 0.f, a2 = 0.f;
        {
            const f4* hp = reinterpret_cast<const f4*>(hb) + kc * 17;  // 68/4
            #pragma unroll
            for (int q = 0; q < 16; ++q) {
                f4 hv4 = hp[q];
                a0 = fmaf(wreg[0][q][0], hv4[0], a0);
                a0 = fmaf(wreg[0][q][1], hv4[1], a0);
                a0 = fmaf(wreg[0][q][2], hv4[2], a0);
                a0 = fmaf(wreg[0][q][3], hv4[3], a0);
                a1 = fmaf(wreg[1][q][0], hv4[0], a1);
                a1 = fmaf(wreg[1][q][1], hv4[1], a1);
                a1 = fmaf(wreg[1][q][2], hv4[2], a1);
                a1 = fmaf(wreg[1][q][3], hv4[3], a1);
                a2 = fmaf(wreg[2][q][0], hv4[0], a2);
                a2 = fmaf(wreg[2][q][1], hv4[1], a2);
                a2 = fmaf(wreg[2][q][2], hv4[2], a2);
                a2 = fmaf(wreg[2][q][3], hv4[3], a2);
            }
        }

        // reduce across the 8 kc lanes (low 3 lane bits)
        #pragma unroll
        for (int off = 1; off < 8; off <<= 1) {
            a0 += __shfl_xor(a0, off, 64);
            a1 += __shfl_xor(a1, off, 64);
            a2 += __shfl_xor(a2, off, 64);
        }

        if (kc == 0) {
            float rr = sigf(xr + a0 + bh0);
            float zz = sigf(xz + a1 + bh1);
            float nn = tanhf(xn + rr * (a2 + bh2));
            float ho = hb[lo];
            float hv = (1.0f - zz) * nn + zz * ho;
            u32x2 pk = (u32x2){__float_as_uint(hv), wg};
            asm volatile("global_store_dwordx2 %0, %1, off sc0 sc1"
                         :: "v"(dst + j), "v"(pk) : "memory");
            hall[(size_t)(b * Tt + t) * Hsz + j] = hv;
            if (t == Tt - 1) hid_out[b * Hsz + j] = hv;
        }
        // no trailing sync: next step stages into the other buffer
    }
}

// ---------------- f16-MFMA GEMM: C[M,N] = A[M,K]_f32 * Wh[N,K]_f16^T + bias ----
__global__ void __launch_bounds__(256) gemm_nt_mfma(
    const float* __restrict__ A,        // [M,K] f32
    const _Float16* __restrict__ Wh,    // [N,K] f16
    const float* __restrict__ bias,     // [N]
    float* __restrict__ C,              // [M,N]
    int M, int N, int K)
{
    const int tid = threadIdx.x;
    const int l   = tid & 63;
    const int w   = tid >> 6;
    const int wm  = w >> 1, wn = w & 1;
    const int m0  = blockIdx.y * 128 + wm * 64;
    const int n0  = blockIdx.x * 128 + wn * 64;
    const int lr  = l & 15;
    const int lk  = (l >> 4) * 8;

    f32x4 acc[4][4];
    #pragma unroll
    for (int mt = 0; mt < 4; ++mt)
        #pragma unroll
        for (int nt = 0; nt < 4; ++nt)
            acc[mt][nt] = (f32x4){0.f, 0.f, 0.f, 0.f};

    for (int ks = 0; ks < K; ks += 32) {
        half8_t af[4], bf[4];
        #pragma unroll
        for (int mt = 0; mt < 4; ++mt) {
            const float* pa = A + (size_t)(m0 + mt * 16 + lr) * K + ks + lk;
            float4 v0 = *reinterpret_cast<const float4*>(pa);
            float4 v1 = *reinterpret_cast<const float4*>(pa + 4);
            half8_t h;
            h[0] = (_Float16)v0.x; h[1] = (_Float16)v0.y;
            h[2] = (_Float16)v0.z; h[3] = (_Float16)v0.w;
            h[4] = (_Float16)v1.x; h[5] = (_Float16)v1.y;
            h[6] = (_Float16)v1.z; h[7] = (_Float16)v1.w;
            af[mt] = h;
        }
        #pragma unroll
        for (int nt = 0; nt < 4; ++nt)
            bf[nt] = *reinterpret_cast<const half8_t*>(Wh + (size_t)(n0 + nt * 16 + lr) * K + ks + lk);
        #pragma unroll
        for (int mt = 0; mt < 4; ++mt)
            #pragma unroll
            for (int nt = 0; nt < 4; ++nt)
                acc[mt][nt] = __builtin_amdgcn_mfma_f32_16x16x32_f16(af[mt], bf[nt], acc[mt][nt], 0, 0, 0);
    }

    #pragma unroll
    for (int nt = 0; nt < 4; ++nt) {
        const int colg = n0 + nt * 16 + lr;
        const float bb = bias[colg];
        #pragma unroll
        for (int mt = 0; mt < 4; ++mt) {
            #pragma unroll
            for (int r = 0; r < 4; ++r) {
                int rowg = m0 + mt * 16 + (l >> 4) * 4 + r;
                C[(size_t)rowg * N + colg] = acc[mt][nt][r] + bb;
            }
        }
    }
}

// ---------------- fp32 GEMM (FC only): C = A * W^T + bias ----------------
#define GM 64
#define GN 64
#define GK 16
__global__ void __launch_bounds__(256) gemm_nt_bias(
    const float* __restrict__ A, const float* __restrict__ W,
    const float* __restrict__ bias, float* __restrict__ C,
    int M, int N, int K)
{
    __shared__ float As[GK][GM];
    __shared__ float Bs[GK][GN];
    const int tid = threadIdx.x;
    const int n0 = blockIdx.x * GN;
    const int m0 = blockIdx.y * GM;
    const int tn = tid & 15;
    const int tm = tid >> 4;
    const int lrow = tid >> 2;
    const int lkq  = tid & 3;

    float acc[4][4];
    #pragma unroll
    for (int i = 0; i < 4; ++i)
        #pragma unroll
        for (int jj = 0; jj < 4; ++jj) acc[i][jj] = 0.0f;

    for (int k0 = 0; k0 < K; k0 += GK) {
        float4 av = *reinterpret_cast<const float4*>(&A[(size_t)(m0 + lrow) * K + k0 + lkq * 4]);
        float4 wv = *reinterpret_cast<const float4*>(&W[(size_t)(n0 + lrow) * K + k0 + lkq * 4]);
        __syncthreads();
        As[lkq * 4 + 0][lrow] = av.x; As[lkq * 4 + 1][lrow] = av.y;
        As[lkq * 4 + 2][lrow] = av.z; As[lkq * 4 + 3][lrow] = av.w;
        Bs[lkq * 4 + 0][lrow] = wv.x; Bs[lkq * 4 + 1][lrow] = wv.y;
        Bs[lkq * 4 + 2][lrow] = wv.z; Bs[lkq * 4 + 3][lrow] = wv.w;
        __syncthreads();
        #pragma unroll
        for (int k = 0; k < GK; ++k) {
            float4 a4 = *reinterpret_cast<const float4*>(&As[k][tm * 4]);
            float4 b4 = *reinterpret_cast<const float4*>(&Bs[k][tn * 4]);
            acc[0][0] = fmaf(a4.x, b4.x, acc[0][0]); acc[0][1] = fmaf(a4.x, b4.y, acc[0][1]);
            acc[0][2] = fmaf(a4.x, b4.z, acc[0][2]); acc[0][3] = fmaf(a4.x, b4.w, acc[0][3]);
            acc[1][0] = fmaf(a4.y, b4.x, acc[1][0]); acc[1][1] = fmaf(a4.y, b4.y, acc[1][1]);
            acc[1][2] = fmaf(a4.y, b4.z, acc[1][2]); acc[1][3] = fmaf(a4.y, b4.w, acc[1][3]);
            acc[2][0] = fmaf(a4.z, b4.x, acc[2][0]); acc[2][1] = fmaf(a4.z, b4.y, acc[2][1]);
            acc[2][2] = fmaf(a4.z, b4.z, acc[2][2]); acc[2][3] = fmaf(a4.z, b4.w, acc[2][3]);
            acc[3][0] = fmaf(a4.w, b4.x, acc[3][0]); acc[3][1] = fmaf(a4.w, b4.y, acc[3][1]);
            acc[3][2] = fmaf(a4.w, b4.z, acc[3][2]); acc[3][3] = fmaf(a4.w, b4.w, acc[3][3]);
        }
    }

    float4 bb = *reinterpret_cast<const float4*>(&bias[n0 + tn * 4]);
    #pragma unroll
    for (int i = 0; i < 4; ++i) {
        int m = m0 + tm * 4 + i;
        float4 o;
        o.x = acc[i][0] + bb.x; o.y = acc[i][1] + bb.y;
        o.z = acc[i][2] + bb.z; o.w = acc[i][3] + bb.w;
        *reinterpret_cast<float4*>(&C[(size_t)m * N + n0 + tn * 4]) = o;
    }
}

// ---------------- host launcher ----------------
extern "C" void kernel_launch(void* const* d_in, const int* in_sizes, int n_in,
                              void* d_out, int out_size, void* d_ws, size_t ws_size,
                              hipStream_t stream) {
    (void)in_sizes; (void)n_in; (void)out_size; (void)ws_size;
    const float* x    = (const float*)d_in[0];
    const float* Wih0 = (const float*)d_in[1];
    const float* Whh0 = (const float*)d_in[2];
    const float* bih0 = (const float*)d_in[3];
    const float* bhh0 = (const float*)d_in[4];
    const float* Wih1 = (const float*)d_in[5];
    const float* Whh1 = (const float*)d_in[6];
    const float* bih1 = (const float*)d_in[7];
    const float* bhh1 = (const float*)d_in[8];
    const float* fcW  = (const float*)d_in[9];
    const float* fcb  = (const float*)d_in[10];

    float* out = (float*)d_out;                       // [B,T,O]
    float* hid = out + (size_t)Bsz * Tt * Osz;        // [L,B,H]

    char* ws = (char*)d_ws;
    const size_t xp_off   = 0;
    const size_t hall_off = xp_off + (size_t)Bsz * Tt * G3 * 4;
    const size_t pbuf_off = hall_off + (size_t)Bsz * Tt * Hsz * 4;
    const size_t w0h_off  = pbuf_off + (size_t)2 * Bsz * Hsz * 8;
    const size_t w1h_off  = w0h_off + (size_t)G3 * Isz * 2;
    float*     xp    = (float*)(ws + xp_off);
    float*     hall  = (float*)(ws + hall_off);
    u32x2*     pbuf  = (u32x2*)(ws + pbuf_off);
    _Float16*  W0h   = (_Float16*)(ws + w0h_off);
    _Float16*  W1h   = (_Float16*)(ws + w1h_off);

    // convert gate-projection weights to f16
    hipLaunchKernelGGL(f32_to_f16, dim3(128), dim3(256), 0, stream, Wih0, W0h, G3 * Isz / 4);
    hipLaunchKernelGGL(f32_to_f16, dim3(256), dim3(256), 0, stream, Wih1, W1h, G3 * Hsz / 4);

    // layer 0 input projection (f16 MFMA): xp = x @ Wih0^T + bih0
    hipLaunchKernelGGL(gemm_nt_mfma, dim3(G3 / 128, (Bsz * Tt) / 128), dim3(256), 0, stream,
                       x, W0h, bih0, xp, Bsz * Tt, G3, Isz);

    // layer 0 recurrence
    hipLaunchKernelGGL(init_pbuf, dim3(64), dim3(256), 0, stream, pbuf, G0_L0);
    hipLaunchKernelGGL(gru_rec, dim3(NBLK), dim3(TPB), 0, stream,
                       xp, Whh0, bhh0, hall, pbuf, hid, G0_L0);

    // layer 1 input projection (f16 MFMA): xp = hall @ Wih1^T + bih1
    hipLaunchKernelGGL(gemm_nt_mfma, dim3(G3 / 128, (Bsz * Tt) / 128), dim3(256), 0, stream,
                       hall, W1h, bih1, xp, Bsz * Tt, G3, Hsz);

    // layer 1 recurrence (overwrites hall)
    hipLaunchKernelGGL(init_pbuf, dim3(64), dim3(256), 0, stream, pbuf, G0_L1);
    hipLaunchKernelGGL(gru_rec, dim3(NBLK), dim3(TPB), 0, stream,
                       xp, Whh1, bhh1, hall, pbuf, hid + Bsz * Hsz, G0_L1);

    // FC (fp32): out = hall @ fcW^T + fcb
    hipLaunchKernelGGL(gemm_nt_bias, dim3(Osz / GN, (Bsz * Tt) / GM), dim3(256), 0, stream,
                       hall, fcW, fcb, out, Bsz * Tt, Osz, Hsz);
}